// Round 1
// baseline (1035.854 us; speedup 1.0000x reference)
//
#include <hip/hip_runtime.h>
#include <stdint.h>

// ---------------------------------------------------------------------------
// Fused: (add+RMSNorm+static fp8 quant) -> fp8 GEMM -> dequant
// T=8192, H=4096, I=8192 (derived from in_sizes at launch)
// d_out = [ out f32 [T][I] | residual_out f32 [T][H] ]
// d_ws  = [ q fp8 [T][H] | w_t fp8 [I][H] ]
// ---------------------------------------------------------------------------

typedef float float4v __attribute__((ext_vector_type(4)));

#define GLOAD_LDS16(gp, lp)                                                    \
    __builtin_amdgcn_global_load_lds(                                          \
        (const __attribute__((address_space(1))) void*)(gp),                   \
        (__attribute__((address_space(3))) void*)(lp), 16, 0, 0)

// ---------------------------------------------------------------------------
// Kernel 1: convert w f32 [K][N] -> fp8 [N][K] (transpose), 64x64 tiles
// ---------------------------------------------------------------------------
__global__ void __launch_bounds__(256) wconv_kernel(
    const float* __restrict__ w, uint8_t* __restrict__ wt, int K, int N) {
    __shared__ uint8_t tile[64 * 64];  // [n_local][k_local]
    const int k0 = blockIdx.y * 64;
    const int n0 = blockIdx.x * 64;
    const int t = threadIdx.x;
    const int c4 = t & 15;   // n-chunk of 4 floats
    const int r = t >> 4;    // k row base (0..15)

#pragma unroll
    for (int p = 0; p < 4; ++p) {
        const int k = r + p * 16;
        const float4 v = *(const float4*)(w + (size_t)(k0 + k) * N + n0 + c4 * 4);
        const int pk0 = __builtin_amdgcn_cvt_pk_fp8_f32(v.x, v.y, 0, false);
        const int pk1 = __builtin_amdgcn_cvt_pk_fp8_f32(v.z, v.w, 0, false);
        tile[(c4 * 4 + 0) * 64 + k] = (uint8_t)(pk0 & 0xff);
        tile[(c4 * 4 + 1) * 64 + k] = (uint8_t)((pk0 >> 8) & 0xff);
        tile[(c4 * 4 + 2) * 64 + k] = (uint8_t)(pk1 & 0xff);
        tile[(c4 * 4 + 3) * 64 + k] = (uint8_t)((pk1 >> 8) & 0xff);
    }
    __syncthreads();
    const int n = t >> 2;
    const int ch = t & 3;
    const uint4 val = *(const uint4*)(&tile[n * 64 + ch * 16]);
    *(uint4*)(wt + (size_t)(n0 + n) * K + k0 + ch * 16) = val;
}

// ---------------------------------------------------------------------------
// Kernel 2: residual_out = hs + res; RMSNorm; q = fp8(norm / scale)
// One block (256 threads) per row, H = 4096 = 4 passes * 256 * 4
// ---------------------------------------------------------------------------
__global__ void __launch_bounds__(256) norm_quant_kernel(
    const float* __restrict__ hs, const float* __restrict__ res,
    const float* __restrict__ nw, const float* __restrict__ scale,
    float* __restrict__ resid_out, uint8_t* __restrict__ q, int H) {
    const int row = blockIdx.x;
    const int t = threadIdx.x;
    const float* hrow = hs + (size_t)row * H;
    const float* rrow = res + (size_t)row * H;
    float* orow = resid_out + (size_t)row * H;

    float4 ro[4];
    float acc = 0.f;
#pragma unroll
    for (int p = 0; p < 4; ++p) {
        const int c = p * 1024 + t * 4;
        const float4 h = *(const float4*)(hrow + c);
        const float4 r = *(const float4*)(rrow + c);
        float4 s;
        s.x = h.x + r.x; s.y = h.y + r.y; s.z = h.z + r.z; s.w = h.w + r.w;
        ro[p] = s;
        *(float4*)(orow + c) = s;
        acc += s.x * s.x + s.y * s.y + s.z * s.z + s.w * s.w;
    }
    // wave reduce (64-wide)
#pragma unroll
    for (int off = 32; off; off >>= 1) acc += __shfl_down(acc, off);
    __shared__ float wsum[4];
    __shared__ float s_inv;
    if ((t & 63) == 0) wsum[t >> 6] = acc;
    __syncthreads();
    if (t == 0) {
        const float tot = wsum[0] + wsum[1] + wsum[2] + wsum[3];
        s_inv = 1.0f / sqrtf(tot / (float)H + 1e-6f);
    }
    __syncthreads();
    const float inv = s_inv;
    const float sval = scale[0];

#pragma unroll
    for (int p = 0; p < 4; ++p) {
        const int c = p * 1024 + t * 4;
        const float4 wv = *(const float4*)(nw + c);
        const float4 s = ro[p];
        float q0 = (s.x * inv * wv.x) / sval;
        float q1 = (s.y * inv * wv.y) / sval;
        float q2 = (s.z * inv * wv.z) / sval;
        float q3 = (s.w * inv * wv.w) / sval;
        q0 = fminf(fmaxf(q0, -448.f), 448.f);
        q1 = fminf(fmaxf(q1, -448.f), 448.f);
        q2 = fminf(fmaxf(q2, -448.f), 448.f);
        q3 = fminf(fmaxf(q3, -448.f), 448.f);
        int pk = __builtin_amdgcn_cvt_pk_fp8_f32(q0, q1, 0, false);
        pk = __builtin_amdgcn_cvt_pk_fp8_f32(q2, q3, pk, true);
        *(uint32_t*)(q + (size_t)row * H + c) = (uint32_t)pk;
    }
}

// ---------------------------------------------------------------------------
// Kernel 3: fp8 GEMM  C[M][N] = (A[M][K] @ B[N][K]^T) * (scale*wscale)
// 128x128 tile, BK=64, 4 waves (2x2, 64x64 each), mfma 16x16x32 fp8
// ---------------------------------------------------------------------------
__global__ void __launch_bounds__(256) gemm_fp8_kernel(
    const uint8_t* __restrict__ A,   // q   [M][K]
    const uint8_t* __restrict__ B,   // w_t [N][K]
    float* __restrict__ C,           // out [M][N]
    const float* __restrict__ scale, const float* __restrict__ wscale,
    int M, int N, int K) {
    __shared__ uint8_t lA[128 * 64];
    __shared__ uint8_t lB[128 * 64];

    const int t = threadIdx.x;
    const int wid = t >> 6;
    const int lane = t & 63;
    const int bm0 = blockIdx.y * 128;
    const int bn0 = blockIdx.x * 128;
    const int wm = wid >> 1;
    const int wn = wid & 1;

    float4v acc[4][4] = {};

    const int rowA = wm * 64 + (lane & 15);
    const int rowB = wn * 64 + (lane & 15);
    const int kfrag = (lane >> 4) * 8;

    // staging indices: 2 rounds x 256 threads x 16B = 8KB per tile
    const int o0 = t * 16;
    const int o1 = (256 + t) * 16;
    const int ar0 = o0 >> 6, ac0 = o0 & 63;
    const int ar1 = o1 >> 6, ac1 = o1 & 63;

    for (int k0 = 0; k0 < K; k0 += 64) {
        GLOAD_LDS16(A + (size_t)(bm0 + ar0) * K + k0 + ac0, lA + o0);
        GLOAD_LDS16(A + (size_t)(bm0 + ar1) * K + k0 + ac1, lA + o1);
        GLOAD_LDS16(B + (size_t)(bn0 + ar0) * K + k0 + ac0, lB + o0);
        GLOAD_LDS16(B + (size_t)(bn0 + ar1) * K + k0 + ac1, lB + o1);
        __syncthreads();

        long a[4][2], b[4][2];
#pragma unroll
        for (int i = 0; i < 4; ++i)
#pragma unroll
            for (int kk = 0; kk < 2; ++kk) {
                a[i][kk] = *(const long*)(lA + (rowA + i * 16) * 64 + kk * 32 + kfrag);
                b[i][kk] = *(const long*)(lB + (rowB + i * 16) * 64 + kk * 32 + kfrag);
            }
#pragma unroll
        for (int kk = 0; kk < 2; ++kk)
#pragma unroll
            for (int i = 0; i < 4; ++i)
#pragma unroll
                for (int j = 0; j < 4; ++j)
                    acc[i][j] = __builtin_amdgcn_mfma_f32_16x16x32_fp8_fp8(
                        a[i][kk], b[j][kk], acc[i][j], 0, 0, 0);
        __syncthreads();
    }

    const float f = scale[0] * wscale[0];
    const int rbase = (lane >> 4) * 4;
    const int col = lane & 15;
#pragma unroll
    for (int i = 0; i < 4; ++i) {
#pragma unroll
        for (int j = 0; j < 4; ++j) {
            const size_t gr = (size_t)(bm0 + wm * 64 + i * 16 + rbase);
            const size_t gc = (size_t)(bn0 + wn * 64 + j * 16 + col);
#pragma unroll
            for (int r = 0; r < 4; ++r)
                C[(gr + r) * N + gc] = acc[i][j][r] * f;
        }
    }
}

// ---------------------------------------------------------------------------
extern "C" void kernel_launch(void* const* d_in, const int* in_sizes, int n_in,
                              void* d_out, int out_size, void* d_ws, size_t ws_size,
                              hipStream_t stream) {
    const float* hs     = (const float*)d_in[0];
    const float* res    = (const float*)d_in[1];
    const float* nw     = (const float*)d_in[2];
    const float* w      = (const float*)d_in[3];
    const float* scale  = (const float*)d_in[4];
    const float* wscale = (const float*)d_in[5];

    const int H = in_sizes[2];
    const int T = in_sizes[0] / H;
    const int I = in_sizes[3] / H;

    float* out       = (float*)d_out;            // [T][I]
    float* resid_out = out + (size_t)T * I;      // [T][H]
    uint8_t* q  = (uint8_t*)d_ws;                // [T][H] fp8
    uint8_t* wt = q + (size_t)T * H;             // [I][H] fp8

    // 1. weight convert + transpose (f32 [H][I] -> fp8 [I][H])
    wconv_kernel<<<dim3(I / 64, H / 64), 256, 0, stream>>>(w, wt, H, I);
    // 2. fused add + RMSNorm + static fp8 quant
    norm_quant_kernel<<<T, 256, 0, stream>>>(hs, res, nw, scale, resid_out, q, H);
    // 3. fp8 GEMM + dequant
    gemm_fp8_kernel<<<dim3(I / 128, T / 128), 256, 0, stream>>>(
        q, wt, out, scale, wscale, T, I, H);
}

// Round 2
// 545.121 us; speedup vs baseline: 1.9002x; 1.9002x over previous
//
#include <hip/hip_runtime.h>
#include <stdint.h>

// ---------------------------------------------------------------------------
// Fused: (add+RMSNorm+static fp8 quant) -> fp8 GEMM -> dequant
// T=8192, H=4096, I=8192 (derived from in_sizes at launch)
// d_out = [ out f32 [T][I] | residual_out f32 [T][H] ]
// d_ws  = [ q fp8 [T][H] | w_t fp8 [I][H] ]
//
// fp8 operand layout (A=q and B=w_t): within each 64-byte K-group of a row,
// 8-byte chunks are stored in order (0,4,1,5,2,6,3,7). A single 16-byte LDS
// read at row*64 + g*16 then yields the mfma k-slice frags for BOTH kk=0
// (k bytes g*8..) and kk=1 (k bytes 32+g*8..) -> conflict-free ds_read_b128
// (banks 16r+4g cover all 32 banks; m97-proven pattern).
// ---------------------------------------------------------------------------

typedef float float4v __attribute__((ext_vector_type(4)));
typedef long  long2v  __attribute__((ext_vector_type(2)));

#define GLOAD_LDS16(gp, lp)                                                    \
    __builtin_amdgcn_global_load_lds(                                          \
        (const __attribute__((address_space(1))) void*)(gp),                   \
        (__attribute__((address_space(3))) void*)(lp), 16, 0, 0)

// ---------------------------------------------------------------------------
// Kernel 1: convert w f32 [K][N] -> fp8 [N][K] (transpose), 64x64 tiles,
// output K-groups chunk-permuted (0,4,1,5,2,6,3,7).
// ---------------------------------------------------------------------------
__global__ void __launch_bounds__(256) wconv_kernel(
    const float* __restrict__ w, uint8_t* __restrict__ wt, int K, int N) {
    __shared__ uint8_t tile[64 * 64];  // [n_local][k_local]
    const int k0 = blockIdx.y * 64;
    const int n0 = blockIdx.x * 64;
    const int t = threadIdx.x;
    const int c4 = t & 15;   // n-chunk of 4 floats
    const int r = t >> 4;    // k row base (0..15)

#pragma unroll
    for (int p = 0; p < 4; ++p) {
        const int k = r + p * 16;
        const float4 v = *(const float4*)(w + (size_t)(k0 + k) * N + n0 + c4 * 4);
        const int pk0 = __builtin_amdgcn_cvt_pk_fp8_f32(v.x, v.y, 0, false);
        const int pk1 = __builtin_amdgcn_cvt_pk_fp8_f32(v.z, v.w, 0, false);
        tile[(c4 * 4 + 0) * 64 + k] = (uint8_t)(pk0 & 0xff);
        tile[(c4 * 4 + 1) * 64 + k] = (uint8_t)((pk0 >> 8) & 0xff);
        tile[(c4 * 4 + 2) * 64 + k] = (uint8_t)(pk1 & 0xff);
        tile[(c4 * 4 + 3) * 64 + k] = (uint8_t)((pk1 >> 8) & 0xff);
    }
    __syncthreads();
    // physical 16-byte group ch holds logical chunks ch and ch+4:
    // k bytes [ch*8, ch*8+8) ++ [32+ch*8, 32+ch*8+8)
    const int n = t >> 2;
    const int ch = t & 3;
    const uint2 lo = *(const uint2*)(&tile[n * 64 + ch * 8]);
    const uint2 hi = *(const uint2*)(&tile[n * 64 + 32 + ch * 8]);
    const uint4 val = make_uint4(lo.x, lo.y, hi.x, hi.y);
    *(uint4*)(wt + (size_t)(n0 + n) * K + k0 + ch * 16) = val;
}

// ---------------------------------------------------------------------------
// Kernel 2: residual_out = hs + res; RMSNorm; q = fp8(norm / scale),
// q stored with per-64B-group chunk permutation (0,4,1,5,2,6,3,7).
// One block (256 threads) per row, H = 4096 = 4 passes * 256 * 4
// ---------------------------------------------------------------------------
__global__ void __launch_bounds__(256) norm_quant_kernel(
    const float* __restrict__ hs, const float* __restrict__ res,
    const float* __restrict__ nw, const float* __restrict__ scale,
    float* __restrict__ resid_out, uint8_t* __restrict__ q, int H) {
    const int row = blockIdx.x;
    const int t = threadIdx.x;
    const float* hrow = hs + (size_t)row * H;
    const float* rrow = res + (size_t)row * H;
    float* orow = resid_out + (size_t)row * H;

    float4 ro[4];
    float acc = 0.f;
#pragma unroll
    for (int p = 0; p < 4; ++p) {
        const int c = p * 1024 + t * 4;
        const float4 h = *(const float4*)(hrow + c);
        const float4 r = *(const float4*)(rrow + c);
        float4 s;
        s.x = h.x + r.x; s.y = h.y + r.y; s.z = h.z + r.z; s.w = h.w + r.w;
        ro[p] = s;
        *(float4*)(orow + c) = s;
        acc += s.x * s.x + s.y * s.y + s.z * s.z + s.w * s.w;
    }
    // wave reduce (64-wide)
#pragma unroll
    for (int off = 32; off; off >>= 1) acc += __shfl_down(acc, off);
    __shared__ float wsum[4];
    __shared__ float s_inv;
    if ((t & 63) == 0) wsum[t >> 6] = acc;
    __syncthreads();
    if (t == 0) {
        const float tot = wsum[0] + wsum[1] + wsum[2] + wsum[3];
        s_inv = 1.0f / sqrtf(tot / (float)H + 1e-6f);
    }
    __syncthreads();
    const float inv = s_inv;
    const float sval = scale[0];

#pragma unroll
    for (int p = 0; p < 4; ++p) {
        const int c = p * 1024 + t * 4;
        const float4 wv = *(const float4*)(nw + c);
        const float4 s = ro[p];
        float q0 = (s.x * inv * wv.x) / sval;
        float q1 = (s.y * inv * wv.y) / sval;
        float q2 = (s.z * inv * wv.z) / sval;
        float q3 = (s.w * inv * wv.w) / sval;
        q0 = fminf(fmaxf(q0, -448.f), 448.f);
        q1 = fminf(fmaxf(q1, -448.f), 448.f);
        q2 = fminf(fmaxf(q2, -448.f), 448.f);
        q3 = fminf(fmaxf(q3, -448.f), 448.f);
        int pk = __builtin_amdgcn_cvt_pk_fp8_f32(q0, q1, 0, false);
        pk = __builtin_amdgcn_cvt_pk_fp8_f32(q2, q3, pk, true);
        // chunk-permuted store: word w -> (lc,h); pc = lc<4 ? 2*lc : 2*(lc-4)+1
        const int w_idx = (c >> 2) & 15;
        const int lc = w_idx >> 1, hh = w_idx & 1;
        const int pc = (lc < 4) ? (lc << 1) : (((lc - 4) << 1) | 1);
        const int off = (c & ~63) | (pc << 3) | (hh << 2);
        *(uint32_t*)(q + (size_t)row * H + off) = (uint32_t)pk;
    }
}

// ---------------------------------------------------------------------------
// Kernel 3: fp8 GEMM  C[M][N] = (A[M][K] @ B[N][K]^T) * (scale*wscale)
// 128x128 tile, BK=64, 4 waves (2x2, 64x64 each), mfma 16x16x32 fp8.
// A,B global layouts chunk-permuted so one ds_read_b128 per (row, g) gives
// both kk frags (see header comment).
// ---------------------------------------------------------------------------
__global__ void __launch_bounds__(256) gemm_fp8_kernel(
    const uint8_t* __restrict__ A,   // q   [M][K] (permuted groups)
    const uint8_t* __restrict__ B,   // w_t [N][K] (permuted groups)
    float* __restrict__ C,           // out [M][N]
    const float* __restrict__ scale, const float* __restrict__ wscale,
    int M, int N, int K) {
    __shared__ uint8_t lA[128 * 64];
    __shared__ uint8_t lB[128 * 64];

    const int t = threadIdx.x;
    const int wid = t >> 6;
    const int lane = t & 63;
    const int bm0 = blockIdx.y * 128;
    const int bn0 = blockIdx.x * 128;
    const int wm = wid >> 1;
    const int wn = wid & 1;

    float4v acc[4][4] = {};

    const int rowA = wm * 64 + (lane & 15);
    const int rowB = wn * 64 + (lane & 15);
    const int g16 = (lane >> 4) * 16;

    // staging indices: 2 rounds x 256 threads x 16B = 8KB per tile
    const int o0 = t * 16;
    const int o1 = (256 + t) * 16;
    const int ar0 = o0 >> 6, ac0 = o0 & 63;
    const int ar1 = o1 >> 6, ac1 = o1 & 63;

    for (int k0 = 0; k0 < K; k0 += 64) {
        GLOAD_LDS16(A + (size_t)(bm0 + ar0) * K + k0 + ac0, lA + o0);
        GLOAD_LDS16(A + (size_t)(bm0 + ar1) * K + k0 + ac1, lA + o1);
        GLOAD_LDS16(B + (size_t)(bn0 + ar0) * K + k0 + ac0, lB + o0);
        GLOAD_LDS16(B + (size_t)(bn0 + ar1) * K + k0 + ac1, lB + o1);
        __syncthreads();

        long2v a[4], b[4];
#pragma unroll
        for (int i = 0; i < 4; ++i) {
            a[i] = *(const long2v*)(lA + (rowA + i * 16) * 64 + g16);
            b[i] = *(const long2v*)(lB + (rowB + i * 16) * 64 + g16);
        }
#pragma unroll
        for (int kk = 0; kk < 2; ++kk)
#pragma unroll
            for (int i = 0; i < 4; ++i)
#pragma unroll
                for (int j = 0; j < 4; ++j)
                    acc[i][j] = __builtin_amdgcn_mfma_f32_16x16x32_fp8_fp8(
                        a[i][kk], b[j][kk], acc[i][j], 0, 0, 0);
        __syncthreads();
    }

    const float f = scale[0] * wscale[0];
    const int rbase = (lane >> 4) * 4;
    const int col = lane & 15;
#pragma unroll
    for (int i = 0; i < 4; ++i) {
#pragma unroll
        for (int j = 0; j < 4; ++j) {
            const size_t gr = (size_t)(bm0 + wm * 64 + i * 16 + rbase);
            const size_t gc = (size_t)(bn0 + wn * 64 + j * 16 + col);
#pragma unroll
            for (int r = 0; r < 4; ++r)
                C[(gr + r) * N + gc] = acc[i][j][r] * f;
        }
    }
}

// ---------------------------------------------------------------------------
extern "C" void kernel_launch(void* const* d_in, const int* in_sizes, int n_in,
                              void* d_out, int out_size, void* d_ws, size_t ws_size,
                              hipStream_t stream) {
    const float* hs     = (const float*)d_in[0];
    const float* res    = (const float*)d_in[1];
    const float* nw     = (const float*)d_in[2];
    const float* w      = (const float*)d_in[3];
    const float* scale  = (const float*)d_in[4];
    const float* wscale = (const float*)d_in[5];

    const int H = in_sizes[2];
    const int T = in_sizes[0] / H;
    const int I = in_sizes[3] / H;

    float* out       = (float*)d_out;            // [T][I]
    float* resid_out = out + (size_t)T * I;      // [T][H]
    uint8_t* q  = (uint8_t*)d_ws;                // [T][H] fp8 (permuted)
    uint8_t* wt = q + (size_t)T * H;             // [I][H] fp8 (permuted)

    // 1. weight convert + transpose (f32 [H][I] -> fp8 [I][H])
    wconv_kernel<<<dim3(I / 64, H / 64), 256, 0, stream>>>(w, wt, H, I);
    // 2. fused add + RMSNorm + static fp8 quant
    norm_quant_kernel<<<T, 256, 0, stream>>>(hs, res, nw, scale, resid_out, q, H);
    // 3. fp8 GEMM + dequant
    gemm_fp8_kernel<<<dim3(I / 128, T / 128), 256, 0, stream>>>(
        q, wt, out, scale, wscale, T, I, H);
}

// Round 3
// 469.615 us; speedup vs baseline: 2.2057x; 1.1608x over previous
//
#include <hip/hip_runtime.h>
#include <stdint.h>

// ---------------------------------------------------------------------------
// Fused: (add+RMSNorm+static fp8 quant) -> MX-fp8 GEMM (scale=1.0) -> dequant
// T=8192, H=4096, I=8192 (derived from in_sizes at launch)
// d_out = [ out f32 [T][I] | residual_out f32 [T][H] ]
// d_ws  = [ q' fp8 frag-tiles | wt' fp8 frag-tiles ]
//
// Fragment-tile layout (both operands; tile = 128 rows x 64 k-bytes = 8 KB,
// the exact LDS image for one GEMM K-step):
//   tile_idx = (row>>7)*(K/64) + (k>>6)
//   chunk c  = s*4 + kc*2 + p   (s=(row>>5)&3, kc=(k>>5)&1, p=(k>>4)&1)
//   offset   = tile_idx*8192 + c*512 + (row&31)*16 + (k&15)
// mfma_scale_f32_32x32x64_f8f6f4 A-frag (lane): row=lane&31,
//   k=(lane>>5)*32 + reg*4 + byte  -> two ds_read_b128 at
//   s*2048 + (lane>>5)*1024 + {0,512} + (lane&31)*16  (lane-linear, 0 conflicts)
// ---------------------------------------------------------------------------

typedef float float16v __attribute__((ext_vector_type(16)));
typedef int   int8v    __attribute__((ext_vector_type(8)));

#define GLOAD_LDS16(gp, lp)                                                    \
    __builtin_amdgcn_global_load_lds(                                          \
        (const __attribute__((address_space(1))) void*)(gp),                   \
        (__attribute__((address_space(3))) void*)(lp), 16, 0, 0)

#define MFMA_SCALE1(a, b, c)                                                   \
    __builtin_amdgcn_mfma_scale_f32_32x32x64_f8f6f4(                           \
        (a), (b), (c), 0, 0, 0, 0x7f7f7f7f, 0, 0x7f7f7f7f)

// ---------------------------------------------------------------------------
// Kernel 1: w f32 [K][N] -> fp8 fragment-tiles wt' (transpose: rows = n)
// 64x64 input tiles.
// ---------------------------------------------------------------------------
__global__ void __launch_bounds__(256) wconv_kernel(
    const float* __restrict__ w, uint8_t* __restrict__ wt, int K, int N) {
    __shared__ uint8_t tile[64 * 64];  // [n_local][k_local]
    const int k0 = blockIdx.y * 64;
    const int n0 = blockIdx.x * 64;
    const int t = threadIdx.x;
    const int c4 = t & 15;   // n-chunk of 4 floats
    const int r = t >> 4;    // k row base (0..15)

#pragma unroll
    for (int p = 0; p < 4; ++p) {
        const int k = r + p * 16;
        const float4 v = *(const float4*)(w + (size_t)(k0 + k) * N + n0 + c4 * 4);
        const int pk0 = __builtin_amdgcn_cvt_pk_fp8_f32(v.x, v.y, 0, false);
        const int pk1 = __builtin_amdgcn_cvt_pk_fp8_f32(v.z, v.w, 0, false);
        tile[(c4 * 4 + 0) * 64 + k] = (uint8_t)(pk0 & 0xff);
        tile[(c4 * 4 + 1) * 64 + k] = (uint8_t)((pk0 >> 8) & 0xff);
        tile[(c4 * 4 + 2) * 64 + k] = (uint8_t)(pk1 & 0xff);
        tile[(c4 * 4 + 3) * 64 + k] = (uint8_t)((pk1 >> 8) & 0xff);
    }
    __syncthreads();
    const int n_local = t >> 2;
    const int ch = t & 3;   // 16B piece within 64B k-group: c = s*4 + ch
    const uint4 val = *(const uint4*)(&tile[n_local * 64 + ch * 16]);
    const int n = n0 + n_local;
    const size_t tile_idx = (size_t)(n >> 7) * (K >> 6) + (k0 >> 6);
    const int c = ((n >> 5) & 3) * 4 + ch;
    *(uint4*)(wt + tile_idx * 8192 + c * 512 + (n & 31) * 16) = val;
}

// ---------------------------------------------------------------------------
// Kernel 2: residual_out = hs + res; RMSNorm; q' = fp8(norm/scale) frag-tiles
// One block (256 threads) per row. Pass1 coalesced + stash in LDS;
// pass2 reads 16 contiguous values per thread -> one 16B frag-tile store.
// ---------------------------------------------------------------------------
__global__ void __launch_bounds__(256) norm_quant_kernel(
    const float* __restrict__ hs, const float* __restrict__ res,
    const float* __restrict__ nw, const float* __restrict__ scale,
    float* __restrict__ resid_out, uint8_t* __restrict__ q, int H) {
    __shared__ float sm[4096];
    __shared__ float wsum[4];
    __shared__ float s_inv;
    const int row = blockIdx.x;
    const int t = threadIdx.x;
    const float* hrow = hs + (size_t)row * H;
    const float* rrow = res + (size_t)row * H;
    float* orow = resid_out + (size_t)row * H;

    float acc = 0.f;
#pragma unroll
    for (int p = 0; p < 4; ++p) {
        const int c = p * 1024 + t * 4;
        const float4 h = *(const float4*)(hrow + c);
        const float4 r = *(const float4*)(rrow + c);
        float4 s;
        s.x = h.x + r.x; s.y = h.y + r.y; s.z = h.z + r.z; s.w = h.w + r.w;
        *(float4*)(orow + c) = s;
        *(float4*)(&sm[c]) = s;
        acc += s.x * s.x + s.y * s.y + s.z * s.z + s.w * s.w;
    }
#pragma unroll
    for (int off = 32; off; off >>= 1) acc += __shfl_down(acc, off);
    if ((t & 63) == 0) wsum[t >> 6] = acc;
    __syncthreads();
    if (t == 0) {
        const float tot = wsum[0] + wsum[1] + wsum[2] + wsum[3];
        s_inv = 1.0f / sqrtf(tot / (float)H + 1e-6f);
    }
    __syncthreads();
    const float inv = s_inv;
    const float sval = scale[0];

    // pass 2: thread t quantizes elements [t*16, t*16+16)
    const int k0 = t * 16;
    uint32_t words[4];
#pragma unroll
    for (int i = 0; i < 4; ++i) {
        const float4 s = *(const float4*)(&sm[k0 + i * 4]);
        const float4 wv = *(const float4*)(nw + k0 + i * 4);
        float q0 = (s.x * inv * wv.x) / sval;
        float q1 = (s.y * inv * wv.y) / sval;
        float q2 = (s.z * inv * wv.z) / sval;
        float q3 = (s.w * inv * wv.w) / sval;
        q0 = fminf(fmaxf(q0, -448.f), 448.f);
        q1 = fminf(fmaxf(q1, -448.f), 448.f);
        q2 = fminf(fmaxf(q2, -448.f), 448.f);
        q3 = fminf(fmaxf(q3, -448.f), 448.f);
        int pk = __builtin_amdgcn_cvt_pk_fp8_f32(q0, q1, 0, false);
        pk = __builtin_amdgcn_cvt_pk_fp8_f32(q2, q3, pk, true);
        words[i] = (uint32_t)pk;
    }
    const int kt = t >> 2;           // k-tile (64B groups)
    const int ch = t & 3;            // 16B piece
    const size_t tile_idx = (size_t)(row >> 7) * (H >> 6) + kt;
    const int c = ((row >> 5) & 3) * 4 + ch;
    uint4 val;
    val.x = words[0]; val.y = words[1]; val.z = words[2]; val.w = words[3];
    *(uint4*)(q + tile_idx * 8192 + c * 512 + (row & 31) * 16) = val;
}

// ---------------------------------------------------------------------------
// Kernel 3: MX-fp8 GEMM  C[M][N] = (A[M][K] @ B[N][K]^T) * (scale*wscale)
// 128x128 tile, BK=128 (2 frag-tiles), 4 waves (2x2, 64x64 each),
// mfma_scale_f32_32x32x64_f8f6f4 with unit e8m0 scales.
// ---------------------------------------------------------------------------
__global__ void __launch_bounds__(256) gemm_fp8_kernel(
    const uint8_t* __restrict__ A,   // q'  frag-tiles
    const uint8_t* __restrict__ B,   // wt' frag-tiles
    float* __restrict__ C,           // out [M][N]
    const float* __restrict__ scale, const float* __restrict__ wscale,
    int M, int N, int K) {
    __shared__ uint8_t lA[16384];
    __shared__ uint8_t lB[16384];

    const int t = threadIdx.x;
    const int wid = t >> 6;
    const int lane = t & 63;

    // XCD-bijective swizzle (gridDim.x % 8 == 0)
    const int id = blockIdx.x;
    const int wg = (id & 7) * ((int)gridDim.x >> 3) + (id >> 3);
    const int nbn = N >> 7;
    const int bm = wg / nbn;
    const int bn = wg % nbn;

    const int wm = wid >> 1;
    const int wn = wid & 1;

    float16v acc[2][2] = {};

    const uint8_t* As = A + (size_t)bm * (K >> 6) * 8192;
    const uint8_t* Bs = B + (size_t)bn * (K >> 6) * 8192;

    const int lrow = (lane & 31) * 16;
    const int lgrp = (lane >> 5) * 1024;
    const int aoff0 = (wm * 2 + 0) * 2048 + lgrp + lrow;
    const int aoff1 = (wm * 2 + 1) * 2048 + lgrp + lrow;
    const int boff0 = (wn * 2 + 0) * 2048 + lgrp + lrow;
    const int boff1 = (wn * 2 + 1) * 2048 + lgrp + lrow;
    const int o16 = t * 16;

    const int nkt = K >> 7;  // BK=128: two 8KB tiles per iteration
    for (int kt = 0; kt < nkt; ++kt) {
        GLOAD_LDS16(As + o16,         lA + o16);
        GLOAD_LDS16(As + 4096 + o16,  lA + 4096 + o16);
        GLOAD_LDS16(As + 8192 + o16,  lA + 8192 + o16);
        GLOAD_LDS16(As + 12288 + o16, lA + 12288 + o16);
        GLOAD_LDS16(Bs + o16,         lB + o16);
        GLOAD_LDS16(Bs + 4096 + o16,  lB + 4096 + o16);
        GLOAD_LDS16(Bs + 8192 + o16,  lB + 8192 + o16);
        GLOAD_LDS16(Bs + 12288 + o16, lB + 12288 + o16);
        As += 16384; Bs += 16384;
        __syncthreads();

#pragma unroll
        for (int half = 0; half < 2; ++half) {
            const int hb = half * 8192;
            const uint4 al0 = *(const uint4*)(lA + hb + aoff0);
            const uint4 ah0 = *(const uint4*)(lA + hb + aoff0 + 512);
            const uint4 al1 = *(const uint4*)(lA + hb + aoff1);
            const uint4 ah1 = *(const uint4*)(lA + hb + aoff1 + 512);
            const uint4 bl0 = *(const uint4*)(lB + hb + boff0);
            const uint4 bh0 = *(const uint4*)(lB + hb + boff0 + 512);
            const uint4 bl1 = *(const uint4*)(lB + hb + boff1);
            const uint4 bh1 = *(const uint4*)(lB + hb + boff1 + 512);
            const int8v a0 = {(int)al0.x, (int)al0.y, (int)al0.z, (int)al0.w,
                              (int)ah0.x, (int)ah0.y, (int)ah0.z, (int)ah0.w};
            const int8v a1 = {(int)al1.x, (int)al1.y, (int)al1.z, (int)al1.w,
                              (int)ah1.x, (int)ah1.y, (int)ah1.z, (int)ah1.w};
            const int8v b0 = {(int)bl0.x, (int)bl0.y, (int)bl0.z, (int)bl0.w,
                              (int)bh0.x, (int)bh0.y, (int)bh0.z, (int)bh0.w};
            const int8v b1 = {(int)bl1.x, (int)bl1.y, (int)bl1.z, (int)bl1.w,
                              (int)bh1.x, (int)bh1.y, (int)bh1.z, (int)bh1.w};
            acc[0][0] = MFMA_SCALE1(a0, b0, acc[0][0]);
            acc[0][1] = MFMA_SCALE1(a0, b1, acc[0][1]);
            acc[1][0] = MFMA_SCALE1(a1, b0, acc[1][0]);
            acc[1][1] = MFMA_SCALE1(a1, b1, acc[1][1]);
        }
        __syncthreads();
    }

    const float f = scale[0] * wscale[0];
    const int col = lane & 31;
    const int rbase = (lane >> 5) * 4;
#pragma unroll
    for (int i = 0; i < 2; ++i) {
#pragma unroll
        for (int j = 0; j < 2; ++j) {
#pragma unroll
            for (int reg = 0; reg < 16; ++reg) {
                const int r = (reg & 3) + 8 * (reg >> 2) + rbase;
                const size_t gr = (size_t)(bm * 128 + wm * 64 + i * 32 + r);
                const size_t gc = (size_t)(bn * 128 + wn * 64 + j * 32 + col);
                C[gr * N + gc] = acc[i][j][reg] * f;
            }
        }
    }
}

// ---------------------------------------------------------------------------
extern "C" void kernel_launch(void* const* d_in, const int* in_sizes, int n_in,
                              void* d_out, int out_size, void* d_ws, size_t ws_size,
                              hipStream_t stream) {
    const float* hs     = (const float*)d_in[0];
    const float* res    = (const float*)d_in[1];
    const float* nw     = (const float*)d_in[2];
    const float* w      = (const float*)d_in[3];
    const float* scale  = (const float*)d_in[4];
    const float* wscale = (const float*)d_in[5];

    const int H = in_sizes[2];
    const int T = in_sizes[0] / H;
    const int I = in_sizes[3] / H;

    float* out       = (float*)d_out;            // [T][I]
    float* resid_out = out + (size_t)T * I;      // [T][H]
    uint8_t* q  = (uint8_t*)d_ws;                // q'  frag-tiles (T*H bytes)
    uint8_t* wt = q + (size_t)T * H;             // wt' frag-tiles (I*H bytes)

    // 1. weight convert + transpose -> fragment tiles
    wconv_kernel<<<dim3(I / 64, H / 64), 256, 0, stream>>>(w, wt, H, I);
    // 2. fused add + RMSNorm + static fp8 quant -> fragment tiles
    norm_quant_kernel<<<T, 256, 0, stream>>>(hs, res, nw, scale, resid_out, q, H);
    // 3. MX-fp8 GEMM + dequant
    gemm_fp8_kernel<<<(T / 128) * (I / 128), 256, 0, stream>>>(
        q, wt, out, scale, wscale, T, I, H);
}

// Round 4
// 464.989 us; speedup vs baseline: 2.2277x; 1.0099x over previous
//
#include <hip/hip_runtime.h>
#include <stdint.h>

// ---------------------------------------------------------------------------
// Fused: (add+RMSNorm+static fp8 quant) -> MX-fp8 GEMM (scale=1.0) -> dequant
// T=8192, H=4096, I=8192 (derived from in_sizes at launch)
// d_out = [ out f32 [T][I] | residual_out f32 [T][H] ]
// d_ws  = [ q' fp8 frag-tiles | wt' fp8 frag-tiles ]
//
// Fragment-tile layout (both operands; tile = 128 rows x 64 k-bytes = 8 KB,
// the exact LDS image for one GEMM K-step sub-panel):
//   tile_idx = (row>>7)*(K/64) + (k>>6)
//   chunk c  = s*4 + kc*2 + p   (s=(row>>5)&3, kc=(k>>5)&1, p=(k>>4)&1)
//   offset   = tile_idx*8192 + c*512 + (row&31)*16 + (k&15)
// mfma_scale_f32_32x32x64_f8f6f4 A-frag (lane): row=lane&31,
//   k=(lane>>5)*32 + reg*4 + byte  -> two ds_read_b128 at
//   s*2048 + (lane>>5)*1024 + {0,512} + (lane&31)*16  (lane-linear, 0 conflicts
//   -- measured SQ_LDS_BANK_CONFLICT == 0 in R3)
//
// GEMM: 256x256 tile, 8 waves (2Mx4N), BK=64, 3-slot LDS rotation (96 KB),
// prefetch depth 2, counted s_waitcnt vmcnt(4) + raw s_barrier per K-step
// (never vmcnt(0) in the loop), 2 phases/step with setprio around MFMA.
// ---------------------------------------------------------------------------

typedef float float16v __attribute__((ext_vector_type(16)));
typedef int   int8v    __attribute__((ext_vector_type(8)));

#define GLOAD_LDS16(gp, lp)                                                    \
    __builtin_amdgcn_global_load_lds(                                          \
        (const __attribute__((address_space(1))) void*)(gp),                   \
        (__attribute__((address_space(3))) void*)(lp), 16, 0, 0)

#define MFMA_SCALE1(a, b, c)                                                   \
    __builtin_amdgcn_mfma_scale_f32_32x32x64_f8f6f4(                           \
        (a), (b), (c), 0, 0, 0, 0x7f7f7f7f, 0, 0x7f7f7f7f)

// ---------------------------------------------------------------------------
// Kernel 1: w f32 [K][N] -> fp8 fragment-tiles wt' (transpose: rows = n)
// ---------------------------------------------------------------------------
__global__ void __launch_bounds__(256) wconv_kernel(
    const float* __restrict__ w, uint8_t* __restrict__ wt, int K, int N) {
    __shared__ uint8_t tile[64 * 64];  // [n_local][k_local]
    const int k0 = blockIdx.y * 64;
    const int n0 = blockIdx.x * 64;
    const int t = threadIdx.x;
    const int c4 = t & 15;   // n-chunk of 4 floats
    const int r = t >> 4;    // k row base (0..15)

#pragma unroll
    for (int p = 0; p < 4; ++p) {
        const int k = r + p * 16;
        const float4 v = *(const float4*)(w + (size_t)(k0 + k) * N + n0 + c4 * 4);
        const int pk0 = __builtin_amdgcn_cvt_pk_fp8_f32(v.x, v.y, 0, false);
        const int pk1 = __builtin_amdgcn_cvt_pk_fp8_f32(v.z, v.w, 0, false);
        tile[(c4 * 4 + 0) * 64 + k] = (uint8_t)(pk0 & 0xff);
        tile[(c4 * 4 + 1) * 64 + k] = (uint8_t)((pk0 >> 8) & 0xff);
        tile[(c4 * 4 + 2) * 64 + k] = (uint8_t)(pk1 & 0xff);
        tile[(c4 * 4 + 3) * 64 + k] = (uint8_t)((pk1 >> 8) & 0xff);
    }
    __syncthreads();
    const int n_local = t >> 2;
    const int ch = t & 3;   // 16B piece within 64B k-group: c = s*4 + ch
    const uint4 val = *(const uint4*)(&tile[n_local * 64 + ch * 16]);
    const int n = n0 + n_local;
    const size_t tile_idx = (size_t)(n >> 7) * (K >> 6) + (k0 >> 6);
    const int c = ((n >> 5) & 3) * 4 + ch;
    *(uint4*)(wt + tile_idx * 8192 + c * 512 + (n & 31) * 16) = val;
}

// ---------------------------------------------------------------------------
// Kernel 2: residual_out = hs + res; RMSNorm; q' = fp8(norm/scale) frag-tiles
// ---------------------------------------------------------------------------
__global__ void __launch_bounds__(256) norm_quant_kernel(
    const float* __restrict__ hs, const float* __restrict__ res,
    const float* __restrict__ nw, const float* __restrict__ scale,
    float* __restrict__ resid_out, uint8_t* __restrict__ q, int H) {
    __shared__ float sm[4096];
    __shared__ float wsum[4];
    __shared__ float s_inv;
    const int row = blockIdx.x;
    const int t = threadIdx.x;
    const float* hrow = hs + (size_t)row * H;
    const float* rrow = res + (size_t)row * H;
    float* orow = resid_out + (size_t)row * H;

    float acc = 0.f;
#pragma unroll
    for (int p = 0; p < 4; ++p) {
        const int c = p * 1024 + t * 4;
        const float4 h = *(const float4*)(hrow + c);
        const float4 r = *(const float4*)(rrow + c);
        float4 s;
        s.x = h.x + r.x; s.y = h.y + r.y; s.z = h.z + r.z; s.w = h.w + r.w;
        *(float4*)(orow + c) = s;
        *(float4*)(&sm[c]) = s;
        acc += s.x * s.x + s.y * s.y + s.z * s.z + s.w * s.w;
    }
#pragma unroll
    for (int off = 32; off; off >>= 1) acc += __shfl_down(acc, off);
    if ((t & 63) == 0) wsum[t >> 6] = acc;
    __syncthreads();
    if (t == 0) {
        const float tot = wsum[0] + wsum[1] + wsum[2] + wsum[3];
        s_inv = 1.0f / sqrtf(tot / (float)H + 1e-6f);
    }
    __syncthreads();
    const float inv = s_inv;
    const float sval = scale[0];

    // pass 2: thread t quantizes elements [t*16, t*16+16)
    const int k0 = t * 16;
    uint32_t words[4];
#pragma unroll
    for (int i = 0; i < 4; ++i) {
        const float4 s = *(const float4*)(&sm[k0 + i * 4]);
        const float4 wv = *(const float4*)(nw + k0 + i * 4);
        float q0 = (s.x * inv * wv.x) / sval;
        float q1 = (s.y * inv * wv.y) / sval;
        float q2 = (s.z * inv * wv.z) / sval;
        float q3 = (s.w * inv * wv.w) / sval;
        q0 = fminf(fmaxf(q0, -448.f), 448.f);
        q1 = fminf(fmaxf(q1, -448.f), 448.f);
        q2 = fminf(fmaxf(q2, -448.f), 448.f);
        q3 = fminf(fmaxf(q3, -448.f), 448.f);
        int pk = __builtin_amdgcn_cvt_pk_fp8_f32(q0, q1, 0, false);
        pk = __builtin_amdgcn_cvt_pk_fp8_f32(q2, q3, pk, true);
        words[i] = (uint32_t)pk;
    }
    const int kt = t >> 2;           // k-tile (64B groups)
    const int ch = t & 3;            // 16B piece
    const size_t tile_idx = (size_t)(row >> 7) * (H >> 6) + kt;
    const int c = ((row >> 5) & 3) * 4 + ch;
    uint4 val;
    val.x = words[0]; val.y = words[1]; val.z = words[2]; val.w = words[3];
    *(uint4*)(q + tile_idx * 8192 + c * 512 + (row & 31) * 16) = val;
}

// ---------------------------------------------------------------------------
// helper: load one 32-byte MFMA operand frag from a 2KB frag sub-block
// ---------------------------------------------------------------------------
static __device__ __forceinline__ int8v ldfrag(const uint8_t* p) {
    const uint4 lo = *(const uint4*)p;
    const uint4 hi = *(const uint4*)(p + 512);
    int8v r = {(int)lo.x, (int)lo.y, (int)lo.z, (int)lo.w,
               (int)hi.x, (int)hi.y, (int)hi.z, (int)hi.w};
    return r;
}

// ---------------------------------------------------------------------------
// Kernel 3: MX-fp8 GEMM  C[M][N] = (A[M][K] @ B[N][K]^T) * (scale*wscale)
// 256x256 tile, 8 waves (2Mx4N, 128x64 each), counted-vmcnt pipeline.
// ---------------------------------------------------------------------------
__global__ void __launch_bounds__(512, 2) gemm_fp8_kernel(
    const uint8_t* __restrict__ A,   // q'  frag-tiles
    const uint8_t* __restrict__ B,   // wt' frag-tiles
    float* __restrict__ C,           // out [M][N]
    const float* __restrict__ scale, const float* __restrict__ wscale,
    int M, int N, int K) {
    // 3 slots x 32 KB: per slot = A0(8K) A1(8K) B0(8K) B1(8K)
    __shared__ uint8_t lds[3 * 32768];

    const int t = threadIdx.x;       // 0..511
    const int wid = t >> 6;          // 0..7
    const int lane = t & 63;
    const int wr = wid >> 2;         // 0..1  (M)
    const int wc = wid & 3;          // 0..3  (N)

    // XCD-bijective swizzle (gridDim.x == 1024, %8 == 0)
    const int id = blockIdx.x;
    const int wg = (id & 7) * ((int)gridDim.x >> 3) + (id >> 3);
    const int nbn = N >> 8;
    const int bm = wg / nbn;
    const int bn = wg % nbn;

    const int nkt = K >> 6;          // 64 K-steps of 64 fp8 elements
    const uint8_t* a0s = A + (size_t)(2 * bm) * nkt * 8192;
    const uint8_t* a1s = a0s + (size_t)nkt * 8192;
    const uint8_t* b0s = B + (size_t)(2 * bn) * nkt * 8192;
    const uint8_t* b1s = b0s + (size_t)nkt * 8192;
    const int o16 = t * 16;          // 512 threads x 16B = one 8KB tile

    // prologue: stage tranches 0,1 into slots 0,1 (4 gloads each)
#pragma unroll
    for (int u = 0; u < 2; ++u) {
        uint8_t* dst = lds + u * 32768;
        const size_t ofs = (size_t)u * 8192 + o16;
        GLOAD_LDS16(a0s + ofs, dst + o16);
        GLOAD_LDS16(a1s + ofs, dst + 8192 + o16);
        GLOAD_LDS16(b0s + ofs, dst + 16384 + o16);
        GLOAD_LDS16(b1s + ofs, dst + 24576 + o16);
    }

    const int lgrp = (lane >> 5) * 1024;
    const int lrow = (lane & 31) * 16;
    int aoff[4], boff[2];
#pragma unroll
    for (int mb = 0; mb < 4; ++mb) {
        const int r32 = wr * 4 + mb;                 // 32-row block 0..7
        aoff[mb] = (r32 >> 2) * 8192 + (r32 & 3) * 2048 + lgrp + lrow;
    }
#pragma unroll
    for (int nb = 0; nb < 2; ++nb) {
        const int c32 = wc * 2 + nb;                 // 32-col block 0..7
        boff[nb] = 16384 + (c32 >> 2) * 8192 + (c32 & 3) * 2048 + lgrp + lrow;
    }

    float16v acc[4][2] = {};

    int cur = 0, pfs = 2;
    for (int kt = 0; kt < nkt; ++kt) {
        // tranche kt landed iff <=4 outstanding (only tranche kt+1 in flight)
        asm volatile("s_waitcnt vmcnt(4)" ::: "memory");
        __builtin_amdgcn_s_barrier();

        const uint8_t* sl = lds + cur * 32768;
        uint8_t* pdst = lds + pfs * 32768;
        // clamp tail prefetch: junk lands in slot (kt+2)%3 which is mod-3
        // distinct from the remaining read slots (kt+1)%3, and slot (kt-1)%3's
        // readers drained (per-phase lgkm waits) before this step's barrier.
        const int pf = (kt + 2 < nkt) ? (kt + 2) : (nkt - 1);
        const size_t pofs = (size_t)pf * 8192 + o16;

        // ---- phase A: frags m0,m1 x n0,n1 ----
        const int8v b0 = ldfrag(sl + boff[0]);
        const int8v b1 = ldfrag(sl + boff[1]);
        const int8v a0 = ldfrag(sl + aoff[0]);
        const int8v a1 = ldfrag(sl + aoff[1]);
        GLOAD_LDS16(a0s + pofs, pdst + o16);
        GLOAD_LDS16(a1s + pofs, pdst + 8192 + o16);
        __builtin_amdgcn_sched_barrier(0);
        __builtin_amdgcn_s_setprio(1);
        acc[0][0] = MFMA_SCALE1(a0, b0, acc[0][0]);
        acc[0][1] = MFMA_SCALE1(a0, b1, acc[0][1]);
        acc[1][0] = MFMA_SCALE1(a1, b0, acc[1][0]);
        acc[1][1] = MFMA_SCALE1(a1, b1, acc[1][1]);
        __builtin_amdgcn_s_setprio(0);

        // ---- phase B: frags m2,m3 x n0,n1 ----
        const int8v a2 = ldfrag(sl + aoff[2]);
        const int8v a3 = ldfrag(sl + aoff[3]);
        GLOAD_LDS16(b0s + pofs, pdst + 16384 + o16);
        GLOAD_LDS16(b1s + pofs, pdst + 24576 + o16);
        __builtin_amdgcn_sched_barrier(0);
        __builtin_amdgcn_s_setprio(1);
        acc[2][0] = MFMA_SCALE1(a2, b0, acc[2][0]);
        acc[2][1] = MFMA_SCALE1(a2, b1, acc[2][1]);
        acc[3][0] = MFMA_SCALE1(a3, b0, acc[3][0]);
        acc[3][1] = MFMA_SCALE1(a3, b1, acc[3][1]);
        __builtin_amdgcn_s_setprio(0);

        cur = (cur == 2) ? 0 : cur + 1;
        pfs = (pfs == 2) ? 0 : pfs + 1;
    }

    // epilogue: C/D 32x32 layout col=lane&31, row=(reg&3)+8*(reg>>2)+4*(lane>>5)
    const float f = scale[0] * wscale[0];
    const int col = lane & 31;
    const int rb4 = (lane >> 5) * 4;
#pragma unroll
    for (int mb = 0; mb < 4; ++mb) {
#pragma unroll
        for (int nb = 0; nb < 2; ++nb) {
#pragma unroll
            for (int reg = 0; reg < 16; ++reg) {
                const int r = (reg & 3) + 8 * (reg >> 2) + rb4;
                const size_t gr = (size_t)(bm * 256 + wr * 128 + mb * 32 + r);
                const size_t gc = (size_t)(bn * 256 + wc * 64 + nb * 32 + col);
                C[gr * N + gc] = acc[mb][nb][reg] * f;
            }
        }
    }
}

// ---------------------------------------------------------------------------
extern "C" void kernel_launch(void* const* d_in, const int* in_sizes, int n_in,
                              void* d_out, int out_size, void* d_ws, size_t ws_size,
                              hipStream_t stream) {
    const float* hs     = (const float*)d_in[0];
    const float* res    = (const float*)d_in[1];
    const float* nw     = (const float*)d_in[2];
    const float* w      = (const float*)d_in[3];
    const float* scale  = (const float*)d_in[4];
    const float* wscale = (const float*)d_in[5];

    const int H = in_sizes[2];
    const int T = in_sizes[0] / H;
    const int I = in_sizes[3] / H;

    float* out       = (float*)d_out;            // [T][I]
    float* resid_out = out + (size_t)T * I;      // [T][H]
    uint8_t* q  = (uint8_t*)d_ws;                // q'  frag-tiles (T*H bytes)
    uint8_t* wt = q + (size_t)T * H;             // wt' frag-tiles (I*H bytes)

    // 1. weight convert + transpose -> fragment tiles
    wconv_kernel<<<dim3(I / 64, H / 64), 256, 0, stream>>>(w, wt, H, I);
    // 2. fused add + RMSNorm + static fp8 quant -> fragment tiles
    norm_quant_kernel<<<T, 256, 0, stream>>>(hs, res, nw, scale, resid_out, q, H);
    // 3. MX-fp8 GEMM + dequant (256x256 tiles, counted-vmcnt pipeline)
    gemm_fp8_kernel<<<(T / 256) * (I / 256), 512, 0, stream>>>(
        q, wt, out, scale, wscale, T, I, H);
}